// Round 13
// baseline (281.482 us; speedup 1.0000x reference)
//
#include <hip/hip_runtime.h>

// NonLocalBlock: B=2, C=256, N=D*H*W=6272, mid=128.
// R13 = R12 proj/comb/epi + attn rebuilt as 8-wave (512-thr) k-half-split:
//  - Every config this session had EXACTLY 1568 attn waves (1.53/SIMD) --
//    waves/SIMD was never varied. Here wave (qs,kh) owns q-strip qs (32 rows)
//    and k-half kh of each 64-key tile: 392 blocks x 8 waves = 3136 waves
//    = 3.06/SIMD, and the per-wave serial chain HALVES (8 QK MFMA, 16-reg
//    softmax, 8 PV MFMA per iter).
//  - (m,l,O) k-half merge at kernel end via stats+Obuf (R0's verified
//    pattern), amortized over ~24 iters; Opart/MLg semantics unchanged.
//  - loop machinery unchanged from R11: K/V reg-prefetch + dbuf, single
//    barrier, in-reg P (pkrtz+permlane32_swap), exp2 domain, defer-max,
//    XCD (b,sp)%8 panel affinity (FETCH at compulsory 9.5MB).
//  - LDS 71680 B (Ks0|Ks1 [64][136], Vt0|Vt1 [128][68], stats 512 f32);
//    cap 2 blocks/CU = 32 waves/CU. launch_bounds(512,4) -> VGPR <= 128.
// ws: Qg f16 | Kg f16 | VtG f16 | attnW f16 | MLg f32 = 13.25 MB.

#define BB  2
#define CC  256
#define NN  6272
#define MID 128
#define KS  4
#define QB  128
#define NT  (NN / 64)
#define LOG2E 1.4426950408889634f

typedef _Float16 half2_t __attribute__((ext_vector_type(2)));
typedef _Float16 half4_t __attribute__((ext_vector_type(4)));
typedef _Float16 half8_t __attribute__((ext_vector_type(8)));
typedef float    floatx16 __attribute__((ext_vector_type(16)));
typedef int      i32x2 __attribute__((ext_vector_type(2)));
typedef unsigned u32x4 __attribute__((ext_vector_type(4)));

__device__ __forceinline__ unsigned pkrtz(float a, float b) {
    return __builtin_bit_cast(unsigned, __builtin_amdgcn_cvt_pkrtz(a, b));
}
__device__ __forceinline__ half8_t cvt8(const float* p) {
    float4 f0 = *(const float4*)p;
    float4 f1 = *(const float4*)(p + 4);
    u32x4 u;
    u[0] = pkrtz(f0.x, f0.y); u[1] = pkrtz(f0.z, f0.w);
    u[2] = pkrtz(f1.x, f1.y); u[3] = pkrtz(f1.z, f1.w);
    return __builtin_bit_cast(half8_t, u);
}

// ---------------------------------------------------------------------------
// Projection (f16 MFMA, split-x, 32-n tiles) — UNCHANGED from R12.
// ---------------------------------------------------------------------------
__global__ __launch_bounds__(256, 2) void proj_kernel(
    const float* __restrict__ x,
    const float* __restrict__ w1, const float* __restrict__ bi1,
    const float* __restrict__ w2, const float* __restrict__ bi2,
    const float* __restrict__ w3, const float* __restrict__ bi3,
    _Float16* __restrict__ Qg, _Float16* __restrict__ Kg, _Float16* __restrict__ VtG)
{
    const int t    = threadIdx.x;
    const int lane = t & 63;
    const int wave = t >> 6;
    const int l31  = lane & 31;
    const int l5   = lane >> 5;
    const int n0   = blockIdx.x * 32;
    const int b    = blockIdx.y;

    __shared__ _Float16 xhi[32 * 260];   // [n][c], stride 260
    __shared__ _Float16 xlo[32 * 260];

    #pragma unroll
    for (int a = t; a < 512; a += 256) {
        int cg = a >> 3, ng = a & 7;
        int c  = cg * 4, n4 = ng * 4;
        const float* xb = x + ((size_t)b * CC + c) * NN + n0 + n4;
        float4 v0 = *(const float4*)(xb);
        float4 v1 = *(const float4*)(xb + NN);
        float4 v2 = *(const float4*)(xb + 2 * (size_t)NN);
        float4 v3 = *(const float4*)(xb + 3 * (size_t)NN);
        const float* pv[4] = {&v0.x, &v1.x, &v2.x, &v3.x};
        #pragma unroll
        for (int nn = 0; nn < 4; ++nn) {
            half4_t h, l;
            #pragma unroll
            for (int ci = 0; ci < 4; ++ci) {
                float f = pv[ci][nn];
                _Float16 hh = (_Float16)f;
                h[ci] = hh;
                l[ci] = (_Float16)(f - (float)hh);
            }
            *(half4_t*)&xhi[(n4 + nn) * 260 + c] = h;
            *(half4_t*)&xlo[(n4 + nn) * 260 + c] = l;
        }
    }
    __syncthreads();

    floatx16 acc[3];
    #pragma unroll
    for (int i = 0; i < 3; ++i)
        #pragma unroll
        for (int j = 0; j < 16; ++j) acc[i][j] = 0.f;

    #pragma unroll
    for (int i = 0; i < 3; ++i) {
        const int tau = wave * 3 + i;
        const int pj = tau >> 2, mt = tau & 3;
        const float* w = (pj == 0) ? w1 : (pj == 1) ? w2 : w3;
        const float* wrow = w + (size_t)(mt * 32 + l31) * CC + l5 * 8;
        const _Float16* xr_hi = xhi + l31 * 260 + l5 * 8;
        const _Float16* xr_lo = xlo + l31 * 260 + l5 * 8;
        #pragma unroll
        for (int ds = 0; ds < 16; ++ds) {
            half8_t wf = cvt8(wrow + ds * 16);
            half8_t ah = *(const half8_t*)(xr_hi + ds * 16);
            half8_t al = *(const half8_t*)(xr_lo + ds * 16);
            if (pj < 2) {
                acc[i] = __builtin_amdgcn_mfma_f32_32x32x16_f16(ah, wf, acc[i], 0, 0, 0);
                acc[i] = __builtin_amdgcn_mfma_f32_32x32x16_f16(al, wf, acc[i], 0, 0, 0);
            } else {
                acc[i] = __builtin_amdgcn_mfma_f32_32x32x16_f16(wf, ah, acc[i], 0, 0, 0);
                acc[i] = __builtin_amdgcn_mfma_f32_32x32x16_f16(wf, al, acc[i], 0, 0, 0);
            }
        }
    }

    #pragma unroll
    for (int i = 0; i < 3; ++i) {
        const int tau = wave * 3 + i;
        const int pj = tau >> 2, mt = tau & 3;
        if (pj < 2) {
            const float bm = ((pj == 0) ? bi1 : bi2)[mt * 32 + l31];
            const float sc = (pj == 0) ? LOG2E : 1.0f;
            _Float16* eo = ((pj == 0) ? Qg : Kg) + (size_t)b * NN * MID;
            #pragma unroll
            for (int j = 0; j < 16; ++j) {
                int n = n0 + (j & 3) + 8 * (j >> 2) + 4 * l5;
                eo[(size_t)n * MID + mt * 32 + l31] = (_Float16)((acc[i][j] + bm) * sc);
            }
        } else {
            _Float16* eo = VtG + (size_t)b * MID * NN;
            #pragma unroll
            for (int j = 0; j < 16; ++j) {
                int m = mt * 32 + (j & 3) + 8 * (j >> 2) + 4 * l5;
                eo[(size_t)m * NN + n0 + l31] = (_Float16)(acc[i][j] + bi3[m]);
            }
        }
    }
}

// ---------------------------------------------------------------------------
// Flash attention partial: 8-wave k-half split. grid 1D 392, block 512.
// Wave (qs = wave>>1, kh = wave&1): q-rows [q0+qs*32,+32), k-half kh of each
// 64-key tile. Per iter: prefetch K/V[kt+1]; QK (8 MFMA) from KBcur; 16-reg
// softmax; ds_write prefetch; PV (8 MFMA) from VBcur; ONE barrier.
// End: k-half (m,l,O) merge via stats+Obuf, f16 store to Opart (=d_out).
// LDS (71680 B): Ks0|Ks1 [64][136] | Vt0|Vt1 [128][68] | stats 512 f32.
// Obuf [128][132] f32 (67584 B) aliases the tile buffers for the merge.
// ---------------------------------------------------------------------------
__global__ __launch_bounds__(512, 4) void attn_kernel(
    const _Float16* __restrict__ Qg, const _Float16* __restrict__ Kg,
    const _Float16* __restrict__ VtG, _Float16* __restrict__ Opart,
    float* __restrict__ MLg)
{
    const int t    = threadIdx.x;
    const int lane = t & 63;
    const int wave = t >> 6;        // 0..7
    const int qs   = wave >> 1;     // q-strip 0..3
    const int kh   = wave & 1;      // k-half 0..1
    const int l31  = lane & 31;
    const int l5   = lane >> 5;
    const int c8   = blockIdx.x & 7;    // (b,sp) combo -> XCD
    const int b    = c8 >> 2;
    const int sp   = c8 & 3;
    const int q0   = (blockIdx.x >> 3) * QB;
    const int kt0  = (NT * sp) / KS;
    const int kt1  = (NT * (sp + 1)) / KS;

    __shared__ __align__(16) char lds[71680];
    _Float16* Ks0 = (_Float16*)lds;               // 64*136 halfs
    _Float16* Ks1 = (_Float16*)(lds + 17408);
    _Float16* Vt0 = (_Float16*)(lds + 34816);     // 128*68 halfs
    _Float16* Vt1 = (_Float16*)(lds + 52224);
    float*  stats = (float*)(lds + 69632);        // 512 f32
    float*  Obuf  = (float*)lds;                  // [128][132] f32 alias

    const _Float16* Qb = Qg + ((size_t)b * NN + q0 + qs * 32) * MID;
    const _Float16* Kb = Kg + (size_t)b * NN * MID;
    const _Float16* Vb = VtG + (size_t)b * MID * NN;

    // Q B-frags: col q = l31, d = ds*16 + l5*8 + j.
    half8_t qf[8];
    #pragma unroll
    for (int ds = 0; ds < 8; ++ds)
        qf[ds] = *(const half8_t*)(Qb + (size_t)l31 * MID + ds * 16 + l5 * 8);

    floatx16 o[4];
    #pragma unroll
    for (int dt = 0; dt < 4; ++dt)
        #pragma unroll
        for (int j = 0; j < 16; ++j) o[dt][j] = 0.f;
    float m_run = -3.0e38f, l_run = 0.f;   // m in log2 domain

    // Staging geometry (512 threads; 2 half8 chunks each for K and V):
    const int krow_t = t >> 4, koff_t = (t & 15) * 8;   // K row = it*32 + krow_t
    const int vd_t   = t >> 3, voff_t = (t & 7) * 8;    // V d   = it*64 + vd_t

    // ---- prologue: stage K[kt0] -> Ks0, V[kt0] -> Vt0 ----
    #pragma unroll
    for (int it = 0; it < 2; ++it) {
        int r = it * 32 + krow_t;
        *(half8_t*)(Ks0 + r * 136 + koff_t) =
            *(const half8_t*)(Kb + (size_t)(kt0 * 64 + r) * MID + koff_t);
    }
    #pragma unroll
    for (int it = 0; it < 2; ++it) {
        int d = it * 64 + vd_t;
        *(half8_t*)(Vt0 + d * 68 + voff_t) =
            *(const half8_t*)(Vb + (size_t)d * NN + kt0 * 64 + voff_t);
    }
    __syncthreads();

    for (int kt = kt0, cbuf = 0; kt < kt1; ++kt, cbuf ^= 1) {
        const int nk = kt * 64;
        _Float16* KBcur = cbuf ? Ks1 : Ks0;
        _Float16* KBnxt = cbuf ? Ks0 : Ks1;
        _Float16* VBcur = cbuf ? Vt1 : Vt0;
        _Float16* VBnxt = cbuf ? Vt0 : Vt1;

        // ---- issue K/V[kt+1] global loads -> regs (EARLY) ----
        const int nk2 = (kt + 1 < kt1) ? nk + 64 : nk;   // tail: harmless reload
        half8_t vreg[2], kreg[2];
        #pragma unroll
        for (int it = 0; it < 2; ++it)
            vreg[it] = *(const half8_t*)(Vb + (size_t)(it * 64 + vd_t) * NN + nk2 + voff_t);
        #pragma unroll
        for (int it = 0; it < 2; ++it)
            kreg[it] = *(const half8_t*)(Kb + (size_t)(nk2 + it * 32 + krow_t) * MID + koff_t);
        __builtin_amdgcn_sched_barrier(0);   // pin the loads above this point

        // ---- S^T (32 k' x 32 q) for this wave's k-half ----
        floatx16 s;
        #pragma unroll
        for (int j = 0; j < 16; ++j) s[j] = 0.f;
        const _Float16* krow = KBcur + (kh * 32 + l31) * 136 + l5 * 8;
        __builtin_amdgcn_s_setprio(1);
        #pragma unroll
        for (int ds = 0; ds < 8; ++ds)
            s = __builtin_amdgcn_mfma_f32_32x32x16_f16(
                    *(const half8_t*)(krow + ds * 16), qf[ds], s, 0, 0, 0);
        __builtin_amdgcn_s_setprio(0);

        // ---- online softmax over the wave's 32 k' ----
        float tmax = s[0];
        #pragma unroll
        for (int j = 1; j < 16; ++j) tmax = fmaxf(tmax, s[j]);
        tmax = fmaxf(tmax, __shfl_xor(tmax, 32));

        if (!__all(tmax <= m_run)) {     // defer-max THR=0 (exact)
            const float m_new = fmaxf(m_run, tmax);
            const float alpha = exp2f(m_run - m_new);
            m_run = m_new;
            l_run *= alpha;
            #pragma unroll
            for (int dt = 0; dt < 4; ++dt)
                #pragma unroll
                for (int j = 0; j < 16; ++j) o[dt][j] *= alpha;
        }

        float psum = 0.f;
        unsigned u0[4], u1[4];
        #pragma unroll
        for (int g = 0; g < 4; ++g) {
            float p0 = exp2f(s[4 * g + 0] - m_run);
            float p1 = exp2f(s[4 * g + 1] - m_run);
            float p2 = exp2f(s[4 * g + 2] - m_run);
            float p3 = exp2f(s[4 * g + 3] - m_run);
            psum += (p0 + p1) + (p2 + p3);
            u0[g] = pkrtz(p0, p1);     // k'' = 8g + 4*l5 + {0,1}
            u1[g] = pkrtz(p2, p3);     // k'' = 8g + 4*l5 + {2,3}
        }
        psum += __shfl_xor(psum, 32);
        l_run += psum;

        // ---- write K/V[kt+1] to the other buffers ----
        #pragma unroll
        for (int it = 0; it < 2; ++it)
            *(half8_t*)(VBnxt + (it * 64 + vd_t) * 68 + voff_t) = vreg[it];
        #pragma unroll
        for (int it = 0; it < 2; ++it)
            *(half8_t*)(KBnxt + (it * 32 + krow_t) * 136 + koff_t) = kreg[it];

        // ---- O^T += V^T . P^T over this wave's 32 keys (2 k-slices) ----
        __builtin_amdgcn_s_setprio(1);
        #pragma unroll
        for (int ks = 0; ks < 2; ++ks) {
            i32x2 rA = __builtin_amdgcn_permlane32_swap(
                           (int)u0[2 * ks], (int)u0[2 * ks + 1], false, false);
            i32x2 rB = __builtin_amdgcn_permlane32_swap(
                           (int)u1[2 * ks], (int)u1[2 * ks + 1], false, false);
            u32x4 pw;
            pw[0] = (unsigned)rA[0]; pw[1] = (unsigned)rB[0];
            pw[2] = (unsigned)rA[1]; pw[3] = (unsigned)rB[1];
            half8_t pf = __builtin_bit_cast(half8_t, pw);
            const _Float16* vcol = VBcur + kh * 32 + ks * 16 + l5 * 8;
            #pragma unroll
            for (int dt = 0; dt < 4; ++dt)
                o[dt] = __builtin_amdgcn_mfma_f32_32x32x16_f16(
                            *(const half8_t*)(vcol + (dt * 32 + l31) * 68), pf,
                            o[dt], 0, 0, 0);
        }
        __builtin_amdgcn_s_setprio(0);

        __syncthreads();   // ONE barrier per iter
    }

    // ---- merge the two k-half partials per q-strip ----
    if (l5 == 0) {
        stats[qs * 64 + kh * 32 + l31]       = m_run;
        stats[256 + qs * 64 + kh * 32 + l31] = l_run;
    }
    __syncthreads();
    const float m_o  = stats[qs * 64 + (1 ^ kh) * 32 + l31];
    const float l_o  = stats[256 + qs * 64 + (1 ^ kh) * 32 + l31];
    const float m_st = fmaxf(m_run, m_o);
    const float sc   = exp2f(m_run - m_st);
    const float l_st = l_run * sc + l_o * exp2f(m_o - m_st);

    if (kh == 0 && l5 == 0) {
        float* mlb = MLg + ((size_t)(b * KS + sp) * 2) * NN;
        mlb[q0 + qs * 32 + l31]      = m_st;
        mlb[NN + q0 + qs * 32 + l31] = l_st;
    }

    // Obuf aliases tile buffers: all waves are past the loop-end barrier.
    if (kh == 1) {
        #pragma unroll
        for (int dt = 0; dt < 4; ++dt)
            #pragma unroll
            for (int j = 0; j < 16; ++j) {
                int d = dt * 32 + (j & 3) + 8 * (j >> 2) + 4 * l5;
                Obuf[(qs * 32 + l31) * 132 + d] = o[dt][j] * sc;
            }
    }
    __syncthreads();
    if (kh == 0) {
        #pragma unroll
        for (int dt = 0; dt < 4; ++dt)
            #pragma unroll
            for (int j = 0; j < 16; ++j) {
                int d = dt * 32 + (j & 3) + 8 * (j >> 2) + 4 * l5;
                Obuf[(qs * 32 + l31) * 132 + d] += o[dt][j] * sc;
            }
    }
    __syncthreads();
    _Float16* Ob = Opart + ((size_t)(b * KS + sp) * NN + q0) * MID;
    #pragma unroll
    for (int it = 0; it < 4; ++it) {
        int c = it * 512 + t;           // 2048 half8-chunks: 128 q-rows x 16
        int q = c >> 4, g = c & 15;
        *(half8_t*)(Ob + (size_t)q * MID + g * 8) = cvt8(Obuf + q * 132 + g * 8);
    }
}

// ---------------------------------------------------------------------------
// Combine the KS partials — UNCHANGED.
// ---------------------------------------------------------------------------
__global__ __launch_bounds__(256, 4) void comb_kernel(
    const _Float16* __restrict__ Opart, const float* __restrict__ MLg,
    _Float16* __restrict__ attnW)
{
    const int t  = threadIdx.x;
    const int b  = blockIdx.y;
    const int q  = blockIdx.x * 32 + (t >> 3);
    const int dg = (t & 7) * 16;

    float mv[KS], lv[KS];
    float m_g = -3.0e38f;
    #pragma unroll
    for (int s = 0; s < KS; ++s) {
        const float* mlb = MLg + ((size_t)(b * KS + s) * 2) * NN;
        mv[s] = mlb[q];
        lv[s] = mlb[NN + q];
        m_g = fmaxf(m_g, mv[s]);
    }
    float lg = 0.f, w[KS];
    #pragma unroll
    for (int s = 0; s < KS; ++s) { w[s] = exp2f(mv[s] - m_g); lg += lv[s] * w[s]; }
    const float inv = 1.0f / lg;

    float acc[16];
    #pragma unroll
    for (int j = 0; j < 16; ++j) acc[j] = 0.f;
    #pragma unroll
    for (int s = 0; s < KS; ++s) {
        const half8_t* Op = (const half8_t*)(Opart + ((size_t)(b * KS + s) * NN + q) * MID + dg);
        half8_t v0 = Op[0], v1 = Op[1];
        #pragma unroll
        for (int j = 0; j < 8; ++j) {
            acc[j]     += (float)v0[j] * w[s];
            acc[8 + j] += (float)v1[j] * w[s];
        }
    }
    half8_t h0, h1;
    #pragma unroll
    for (int j = 0; j < 8; ++j) {
        h0[j] = (_Float16)(acc[j] * inv);
        h1[j] = (_Float16)(acc[8 + j] * inv);
    }
    half8_t* Ow = (half8_t*)(attnW + ((size_t)b * NN + q) * MID + dg);
    Ow[0] = h0; Ow[1] = h1;
}

// ---------------------------------------------------------------------------
// Epilogue (f16 MFMA, no LDS, 32-n tiles) — UNCHANGED from R12.
// ---------------------------------------------------------------------------
__global__ __launch_bounds__(256, 2) void epi_kernel(
    const _Float16* __restrict__ attnW, const float* __restrict__ w4,
    const float* __restrict__ b4, const float* __restrict__ x,
    float* __restrict__ out)
{
    const int t    = threadIdx.x;
    const int lane = t & 63;
    const int wave = t >> 6;
    const int l31  = lane & 31;
    const int l5   = lane >> 5;
    const int n0   = blockIdx.x * 32;
    const int b    = blockIdx.y;

    half8_t bf[8];
    const _Float16* brow = attnW + ((size_t)b * NN + n0 + l31) * MID + l5 * 8;
    #pragma unroll
    for (int ds = 0; ds < 8; ++ds)
        bf[ds] = *(const half8_t*)(brow + ds * 16);

    #pragma unroll
    for (int i = 0; i < 2; ++i) {
        const int ct = wave * 2 + i;
        floatx16 acc;
        #pragma unroll
        for (int j = 0; j < 16; ++j) acc[j] = 0.f;

        const float* wrow = w4 + (size_t)(ct * 32 + l31) * MID + l5 * 8;
        #pragma unroll
        for (int ds = 0; ds < 8; ++ds) {
            half8_t wf = cvt8(wrow + ds * 16);
            acc = __builtin_amdgcn_mfma_f32_32x32x16_f16(wf, bf[ds], acc, 0, 0, 0);
        }
        #pragma unroll
        for (int j = 0; j < 16; ++j) {
            int c = ct * 32 + (j & 3) + 8 * (j >> 2) + 4 * l5;
            size_t off = ((size_t)b * CC + c) * NN + n0 + l31;
            out[off] = acc[j] + b4[c] + x[off];
        }
    }
}

extern "C" void kernel_launch(void* const* d_in, const int* in_sizes, int n_in,
                              void* d_out, int out_size, void* d_ws, size_t ws_size,
                              hipStream_t stream)
{
    const float* x  = (const float*)d_in[0];
    const float* w1 = (const float*)d_in[1];
    const float* b1 = (const float*)d_in[2];
    const float* w2 = (const float*)d_in[3];
    const float* b2 = (const float*)d_in[4];
    const float* w3 = (const float*)d_in[5];
    const float* b3 = (const float*)d_in[6];
    const float* w4 = (const float*)d_in[7];
    const float* b4 = (const float*)d_in[8];
    float* out = (float*)d_out;

    // ws: Qg f16 | Kg f16 | VtG f16 | attnW f16 | MLg f32 (13.25 MB total)
    // Opart f16 [B][KS][N][128] aliases d_out (KS=4: exactly out_size).
    _Float16* Qg    = (_Float16*)d_ws;
    _Float16* Kg    = Qg + (size_t)BB * NN * MID;
    _Float16* VtG   = Kg + (size_t)BB * NN * MID;
    _Float16* attnW = VtG + (size_t)BB * NN * MID;
    float* MLg      = (float*)(attnW + (size_t)BB * NN * MID);
    _Float16* Opart = (_Float16*)d_out;

    proj_kernel<<<dim3(NN / 32, BB), 256, 0, stream>>>(x, w1, b1, w2, b2, w3, b3, Qg, Kg, VtG);
    // 1D grid: 49 q-blocks x 8 (b,sp); id = q*8 + c so c lands on XCD c.
    attn_kernel<<<dim3((NN / QB) * KS * BB), 512, 0, stream>>>(Qg, Kg, VtG, Opart, MLg);
    comb_kernel<<<dim3(NN / 32, BB), 256, 0, stream>>>(Opart, MLg, attnW);
    epi_kernel<<<dim3(NN / 32, BB), 256, 0, stream>>>(attnW, w4, b4, x, out);
}

// Round 14
// 280.086 us; speedup vs baseline: 1.0050x; 1.0050x over previous
//
#include <hip/hip_runtime.h>

// NonLocalBlock: B=2, C=256, N=D*H*W=6272, mid=128.
// R14 = R13 with ONE fix: attn __launch_bounds__(512,4) -> (512,2).
//  - R13's (512,4) put the allocator in the 64-VGPR class; per-thread state
//    (o[4]=64 f32 + frags) spilled to scratch: VGPR_Count=64, FETCH 9.5->25.5MB,
//    WRITE 12.9->43.5MB (scratch round-trips), dur 145->169us. The 2x-occupancy
//    experiment was corrupted by spill, not refuted.
//  - (512,2): VGPR cap 256 (expect ~100-112, no spill). Occupancy stays
//    LDS-capped at 2 blocks/CU (71680B) = 4 waves/SIMD capacity; grid 392
//    -> 3.06 waves/SIMD avg, 2x all pre-R13 rounds, now uncorrupted.
//  - Everything else byte-identical to R13 (8-wave k-half split attn;
//    R12 proj/comb/epi; XCD panel swizzle; dbuf; in-reg P; exp2; defer-max).
// ws: Qg f16 | Kg f16 | VtG f16 | attnW f16 | MLg f32 = 13.25 MB.

#define BB  2
#define CC  256
#define NN  6272
#define MID 128
#define KS  4
#define QB  128
#define NT  (NN / 64)
#define LOG2E 1.4426950408889634f

typedef _Float16 half2_t __attribute__((ext_vector_type(2)));
typedef _Float16 half4_t __attribute__((ext_vector_type(4)));
typedef _Float16 half8_t __attribute__((ext_vector_type(8)));
typedef float    floatx16 __attribute__((ext_vector_type(16)));
typedef int      i32x2 __attribute__((ext_vector_type(2)));
typedef unsigned u32x4 __attribute__((ext_vector_type(4)));

__device__ __forceinline__ unsigned pkrtz(float a, float b) {
    return __builtin_bit_cast(unsigned, __builtin_amdgcn_cvt_pkrtz(a, b));
}
__device__ __forceinline__ half8_t cvt8(const float* p) {
    float4 f0 = *(const float4*)p;
    float4 f1 = *(const float4*)(p + 4);
    u32x4 u;
    u[0] = pkrtz(f0.x, f0.y); u[1] = pkrtz(f0.z, f0.w);
    u[2] = pkrtz(f1.x, f1.y); u[3] = pkrtz(f1.z, f1.w);
    return __builtin_bit_cast(half8_t, u);
}

// ---------------------------------------------------------------------------
// Projection (f16 MFMA, split-x, 32-n tiles) — UNCHANGED from R12.
// ---------------------------------------------------------------------------
__global__ __launch_bounds__(256, 2) void proj_kernel(
    const float* __restrict__ x,
    const float* __restrict__ w1, const float* __restrict__ bi1,
    const float* __restrict__ w2, const float* __restrict__ bi2,
    const float* __restrict__ w3, const float* __restrict__ bi3,
    _Float16* __restrict__ Qg, _Float16* __restrict__ Kg, _Float16* __restrict__ VtG)
{
    const int t    = threadIdx.x;
    const int lane = t & 63;
    const int wave = t >> 6;
    const int l31  = lane & 31;
    const int l5   = lane >> 5;
    const int n0   = blockIdx.x * 32;
    const int b    = blockIdx.y;

    __shared__ _Float16 xhi[32 * 260];   // [n][c], stride 260
    __shared__ _Float16 xlo[32 * 260];

    #pragma unroll
    for (int a = t; a < 512; a += 256) {
        int cg = a >> 3, ng = a & 7;
        int c  = cg * 4, n4 = ng * 4;
        const float* xb = x + ((size_t)b * CC + c) * NN + n0 + n4;
        float4 v0 = *(const float4*)(xb);
        float4 v1 = *(const float4*)(xb + NN);
        float4 v2 = *(const float4*)(xb + 2 * (size_t)NN);
        float4 v3 = *(const float4*)(xb + 3 * (size_t)NN);
        const float* pv[4] = {&v0.x, &v1.x, &v2.x, &v3.x};
        #pragma unroll
        for (int nn = 0; nn < 4; ++nn) {
            half4_t h, l;
            #pragma unroll
            for (int ci = 0; ci < 4; ++ci) {
                float f = pv[ci][nn];
                _Float16 hh = (_Float16)f;
                h[ci] = hh;
                l[ci] = (_Float16)(f - (float)hh);
            }
            *(half4_t*)&xhi[(n4 + nn) * 260 + c] = h;
            *(half4_t*)&xlo[(n4 + nn) * 260 + c] = l;
        }
    }
    __syncthreads();

    floatx16 acc[3];
    #pragma unroll
    for (int i = 0; i < 3; ++i)
        #pragma unroll
        for (int j = 0; j < 16; ++j) acc[i][j] = 0.f;

    #pragma unroll
    for (int i = 0; i < 3; ++i) {
        const int tau = wave * 3 + i;
        const int pj = tau >> 2, mt = tau & 3;
        const float* w = (pj == 0) ? w1 : (pj == 1) ? w2 : w3;
        const float* wrow = w + (size_t)(mt * 32 + l31) * CC + l5 * 8;
        const _Float16* xr_hi = xhi + l31 * 260 + l5 * 8;
        const _Float16* xr_lo = xlo + l31 * 260 + l5 * 8;
        #pragma unroll
        for (int ds = 0; ds < 16; ++ds) {
            half8_t wf = cvt8(wrow + ds * 16);
            half8_t ah = *(const half8_t*)(xr_hi + ds * 16);
            half8_t al = *(const half8_t*)(xr_lo + ds * 16);
            if (pj < 2) {
                acc[i] = __builtin_amdgcn_mfma_f32_32x32x16_f16(ah, wf, acc[i], 0, 0, 0);
                acc[i] = __builtin_amdgcn_mfma_f32_32x32x16_f16(al, wf, acc[i], 0, 0, 0);
            } else {
                acc[i] = __builtin_amdgcn_mfma_f32_32x32x16_f16(wf, ah, acc[i], 0, 0, 0);
                acc[i] = __builtin_amdgcn_mfma_f32_32x32x16_f16(wf, al, acc[i], 0, 0, 0);
            }
        }
    }

    #pragma unroll
    for (int i = 0; i < 3; ++i) {
        const int tau = wave * 3 + i;
        const int pj = tau >> 2, mt = tau & 3;
        if (pj < 2) {
            const float bm = ((pj == 0) ? bi1 : bi2)[mt * 32 + l31];
            const float sc = (pj == 0) ? LOG2E : 1.0f;
            _Float16* eo = ((pj == 0) ? Qg : Kg) + (size_t)b * NN * MID;
            #pragma unroll
            for (int j = 0; j < 16; ++j) {
                int n = n0 + (j & 3) + 8 * (j >> 2) + 4 * l5;
                eo[(size_t)n * MID + mt * 32 + l31] = (_Float16)((acc[i][j] + bm) * sc);
            }
        } else {
            _Float16* eo = VtG + (size_t)b * MID * NN;
            #pragma unroll
            for (int j = 0; j < 16; ++j) {
                int m = mt * 32 + (j & 3) + 8 * (j >> 2) + 4 * l5;
                eo[(size_t)m * NN + n0 + l31] = (_Float16)(acc[i][j] + bi3[m]);
            }
        }
    }
}

// ---------------------------------------------------------------------------
// Flash attention partial: 8-wave k-half split. grid 1D 392, block 512.
// Wave (qs = wave>>1, kh = wave&1): q-rows [q0+qs*32,+32), k-half kh of each
// 64-key tile. Per iter: prefetch K/V[kt+1]; QK (8 MFMA) from KBcur; 16-reg
// softmax; ds_write prefetch; PV (8 MFMA) from VBcur; ONE barrier.
// End: k-half (m,l,O) merge via stats+Obuf, f16 store to Opart (=d_out).
// LDS (71680 B): Ks0|Ks1 [64][136] | Vt0|Vt1 [128][68] | stats 512 f32.
// Obuf [128][132] f32 (67584 B) aliases the tile buffers for the merge.
// launch_bounds(512,2): VGPR cap 256 (R13's (512,4) forced 64 -> spill).
// ---------------------------------------------------------------------------
__global__ __launch_bounds__(512, 2) void attn_kernel(
    const _Float16* __restrict__ Qg, const _Float16* __restrict__ Kg,
    const _Float16* __restrict__ VtG, _Float16* __restrict__ Opart,
    float* __restrict__ MLg)
{
    const int t    = threadIdx.x;
    const int lane = t & 63;
    const int wave = t >> 6;        // 0..7
    const int qs   = wave >> 1;     // q-strip 0..3
    const int kh   = wave & 1;      // k-half 0..1
    const int l31  = lane & 31;
    const int l5   = lane >> 5;
    const int c8   = blockIdx.x & 7;    // (b,sp) combo -> XCD
    const int b    = c8 >> 2;
    const int sp   = c8 & 3;
    const int q0   = (blockIdx.x >> 3) * QB;
    const int kt0  = (NT * sp) / KS;
    const int kt1  = (NT * (sp + 1)) / KS;

    __shared__ __align__(16) char lds[71680];
    _Float16* Ks0 = (_Float16*)lds;               // 64*136 halfs
    _Float16* Ks1 = (_Float16*)(lds + 17408);
    _Float16* Vt0 = (_Float16*)(lds + 34816);     // 128*68 halfs
    _Float16* Vt1 = (_Float16*)(lds + 52224);
    float*  stats = (float*)(lds + 69632);        // 512 f32
    float*  Obuf  = (float*)lds;                  // [128][132] f32 alias

    const _Float16* Qb = Qg + ((size_t)b * NN + q0 + qs * 32) * MID;
    const _Float16* Kb = Kg + (size_t)b * NN * MID;
    const _Float16* Vb = VtG + (size_t)b * MID * NN;

    // Q B-frags: col q = l31, d = ds*16 + l5*8 + j.
    half8_t qf[8];
    #pragma unroll
    for (int ds = 0; ds < 8; ++ds)
        qf[ds] = *(const half8_t*)(Qb + (size_t)l31 * MID + ds * 16 + l5 * 8);

    floatx16 o[4];
    #pragma unroll
    for (int dt = 0; dt < 4; ++dt)
        #pragma unroll
        for (int j = 0; j < 16; ++j) o[dt][j] = 0.f;
    float m_run = -3.0e38f, l_run = 0.f;   // m in log2 domain

    // Staging geometry (512 threads; 2 half8 chunks each for K and V):
    const int krow_t = t >> 4, koff_t = (t & 15) * 8;   // K row = it*32 + krow_t
    const int vd_t   = t >> 3, voff_t = (t & 7) * 8;    // V d   = it*64 + vd_t

    // ---- prologue: stage K[kt0] -> Ks0, V[kt0] -> Vt0 ----
    #pragma unroll
    for (int it = 0; it < 2; ++it) {
        int r = it * 32 + krow_t;
        *(half8_t*)(Ks0 + r * 136 + koff_t) =
            *(const half8_t*)(Kb + (size_t)(kt0 * 64 + r) * MID + koff_t);
    }
    #pragma unroll
    for (int it = 0; it < 2; ++it) {
        int d = it * 64 + vd_t;
        *(half8_t*)(Vt0 + d * 68 + voff_t) =
            *(const half8_t*)(Vb + (size_t)d * NN + kt0 * 64 + voff_t);
    }
    __syncthreads();

    for (int kt = kt0, cbuf = 0; kt < kt1; ++kt, cbuf ^= 1) {
        const int nk = kt * 64;
        _Float16* KBcur = cbuf ? Ks1 : Ks0;
        _Float16* KBnxt = cbuf ? Ks0 : Ks1;
        _Float16* VBcur = cbuf ? Vt1 : Vt0;
        _Float16* VBnxt = cbuf ? Vt0 : Vt1;

        // ---- issue K/V[kt+1] global loads -> regs (EARLY) ----
        const int nk2 = (kt + 1 < kt1) ? nk + 64 : nk;   // tail: harmless reload
        half8_t vreg[2], kreg[2];
        #pragma unroll
        for (int it = 0; it < 2; ++it)
            vreg[it] = *(const half8_t*)(Vb + (size_t)(it * 64 + vd_t) * NN + nk2 + voff_t);
        #pragma unroll
        for (int it = 0; it < 2; ++it)
            kreg[it] = *(const half8_t*)(Kb + (size_t)(nk2 + it * 32 + krow_t) * MID + koff_t);
        __builtin_amdgcn_sched_barrier(0);   // pin the loads above this point

        // ---- S^T (32 k' x 32 q) for this wave's k-half ----
        floatx16 s;
        #pragma unroll
        for (int j = 0; j < 16; ++j) s[j] = 0.f;
        const _Float16* krow = KBcur + (kh * 32 + l31) * 136 + l5 * 8;
        __builtin_amdgcn_s_setprio(1);
        #pragma unroll
        for (int ds = 0; ds < 8; ++ds)
            s = __builtin_amdgcn_mfma_f32_32x32x16_f16(
                    *(const half8_t*)(krow + ds * 16), qf[ds], s, 0, 0, 0);
        __builtin_amdgcn_s_setprio(0);

        // ---- online softmax over the wave's 32 k' ----
        float tmax = s[0];
        #pragma unroll
        for (int j = 1; j < 16; ++j) tmax = fmaxf(tmax, s[j]);
        tmax = fmaxf(tmax, __shfl_xor(tmax, 32));

        if (!__all(tmax <= m_run)) {     // defer-max THR=0 (exact)
            const float m_new = fmaxf(m_run, tmax);
            const float alpha = exp2f(m_run - m_new);
            m_run = m_new;
            l_run *= alpha;
            #pragma unroll
            for (int dt = 0; dt < 4; ++dt)
                #pragma unroll
                for (int j = 0; j < 16; ++j) o[dt][j] *= alpha;
        }

        float psum = 0.f;
        unsigned u0[4], u1[4];
        #pragma unroll
        for (int g = 0; g < 4; ++g) {
            float p0 = exp2f(s[4 * g + 0] - m_run);
            float p1 = exp2f(s[4 * g + 1] - m_run);
            float p2 = exp2f(s[4 * g + 2] - m_run);
            float p3 = exp2f(s[4 * g + 3] - m_run);
            psum += (p0 + p1) + (p2 + p3);
            u0[g] = pkrtz(p0, p1);     // k'' = 8g + 4*l5 + {0,1}
            u1[g] = pkrtz(p2, p3);     // k'' = 8g + 4*l5 + {2,3}
        }
        psum += __shfl_xor(psum, 32);
        l_run += psum;

        // ---- write K/V[kt+1] to the other buffers ----
        #pragma unroll
        for (int it = 0; it < 2; ++it)
            *(half8_t*)(VBnxt + (it * 64 + vd_t) * 68 + voff_t) = vreg[it];
        #pragma unroll
        for (int it = 0; it < 2; ++it)
            *(half8_t*)(KBnxt + (it * 32 + krow_t) * 136 + koff_t) = kreg[it];

        // ---- O^T += V^T . P^T over this wave's 32 keys (2 k-slices) ----
        __builtin_amdgcn_s_setprio(1);
        #pragma unroll
        for (int ks = 0; ks < 2; ++ks) {
            i32x2 rA = __builtin_amdgcn_permlane32_swap(
                           (int)u0[2 * ks], (int)u0[2 * ks + 1], false, false);
            i32x2 rB = __builtin_amdgcn_permlane32_swap(
                           (int)u1[2 * ks], (int)u1[2 * ks + 1], false, false);
            u32x4 pw;
            pw[0] = (unsigned)rA[0]; pw[1] = (unsigned)rB[0];
            pw[2] = (unsigned)rA[1]; pw[3] = (unsigned)rB[1];
            half8_t pf = __builtin_bit_cast(half8_t, pw);
            const _Float16* vcol = VBcur + kh * 32 + ks * 16 + l5 * 8;
            #pragma unroll
            for (int dt = 0; dt < 4; ++dt)
                o[dt] = __builtin_amdgcn_mfma_f32_32x32x16_f16(
                            *(const half8_t*)(vcol + (dt * 32 + l31) * 68), pf,
                            o[dt], 0, 0, 0);
        }
        __builtin_amdgcn_s_setprio(0);

        __syncthreads();   // ONE barrier per iter
    }

    // ---- merge the two k-half partials per q-strip ----
    if (l5 == 0) {
        stats[qs * 64 + kh * 32 + l31]       = m_run;
        stats[256 + qs * 64 + kh * 32 + l31] = l_run;
    }
    __syncthreads();
    const float m_o  = stats[qs * 64 + (1 ^ kh) * 32 + l31];
    const float l_o  = stats[256 + qs * 64 + (1 ^ kh) * 32 + l31];
    const float m_st = fmaxf(m_run, m_o);
    const float sc   = exp2f(m_run - m_st);
    const float l_st = l_run * sc + l_o * exp2f(m_o - m_st);

    if (kh == 0 && l5 == 0) {
        float* mlb = MLg + ((size_t)(b * KS + sp) * 2) * NN;
        mlb[q0 + qs * 32 + l31]      = m_st;
        mlb[NN + q0 + qs * 32 + l31] = l_st;
    }

    // Obuf aliases tile buffers: all waves are past the loop-end barrier.
    if (kh == 1) {
        #pragma unroll
        for (int dt = 0; dt < 4; ++dt)
            #pragma unroll
            for (int j = 0; j < 16; ++j) {
                int d = dt * 32 + (j & 3) + 8 * (j >> 2) + 4 * l5;
                Obuf[(qs * 32 + l31) * 132 + d] = o[dt][j] * sc;
            }
    }
    __syncthreads();
    if (kh == 0) {
        #pragma unroll
        for (int dt = 0; dt < 4; ++dt)
            #pragma unroll
            for (int j = 0; j < 16; ++j) {
                int d = dt * 32 + (j & 3) + 8 * (j >> 2) + 4 * l5;
                Obuf[(qs * 32 + l31) * 132 + d] += o[dt][j] * sc;
            }
    }
    __syncthreads();
    _Float16* Ob = Opart + ((size_t)(b * KS + sp) * NN + q0) * MID;
    #pragma unroll
    for (int it = 0; it < 4; ++it) {
        int c = it * 512 + t;           // 2048 half8-chunks: 128 q-rows x 16
        int q = c >> 4, g = c & 15;
        *(half8_t*)(Ob + (size_t)q * MID + g * 8) = cvt8(Obuf + q * 132 + g * 8);
    }
}

// ---------------------------------------------------------------------------
// Combine the KS partials — UNCHANGED.
// ---------------------------------------------------------------------------
__global__ __launch_bounds__(256, 4) void comb_kernel(
    const _Float16* __restrict__ Opart, const float* __restrict__ MLg,
    _Float16* __restrict__ attnW)
{
    const int t  = threadIdx.x;
    const int b  = blockIdx.y;
    const int q  = blockIdx.x * 32 + (t >> 3);
    const int dg = (t & 7) * 16;

    float mv[KS], lv[KS];
    float m_g = -3.0e38f;
    #pragma unroll
    for (int s = 0; s < KS; ++s) {
        const float* mlb = MLg + ((size_t)(b * KS + s) * 2) * NN;
        mv[s] = mlb[q];
        lv[s] = mlb[NN + q];
        m_g = fmaxf(m_g, mv[s]);
    }
    float lg = 0.f, w[KS];
    #pragma unroll
    for (int s = 0; s < KS; ++s) { w[s] = exp2f(mv[s] - m_g); lg += lv[s] * w[s]; }
    const float inv = 1.0f / lg;

    float acc[16];
    #pragma unroll
    for (int j = 0; j < 16; ++j) acc[j] = 0.f;
    #pragma unroll
    for (int s = 0; s < KS; ++s) {
        const half8_t* Op = (const half8_t*)(Opart + ((size_t)(b * KS + s) * NN + q) * MID + dg);
        half8_t v0 = Op[0], v1 = Op[1];
        #pragma unroll
        for (int j = 0; j < 8; ++j) {
            acc[j]     += (float)v0[j] * w[s];
            acc[8 + j] += (float)v1[j] * w[s];
        }
    }
    half8_t h0, h1;
    #pragma unroll
    for (int j = 0; j < 8; ++j) {
        h0[j] = (_Float16)(acc[j] * inv);
        h1[j] = (_Float16)(acc[8 + j] * inv);
    }
    half8_t* Ow = (half8_t*)(attnW + ((size_t)b * NN + q) * MID + dg);
    Ow[0] = h0; Ow[1] = h1;
}

// ---------------------------------------------------------------------------
// Epilogue (f16 MFMA, no LDS, 32-n tiles) — UNCHANGED from R12.
// ---------------------------------------------------------------------------
__global__ __launch_bounds__(256, 2) void epi_kernel(
    const _Float16* __restrict__ attnW, const float* __restrict__ w4,
    const float* __restrict__ b4, const float* __restrict__ x,
    float* __restrict__ out)
{
    const int t    = threadIdx.x;
    const int lane = t & 63;
    const int wave = t >> 6;
    const int l31  = lane & 31;
    const int l5   = lane >> 5;
    const int n0   = blockIdx.x * 32;
    const int b    = blockIdx.y;

    half8_t bf[8];
    const _Float16* brow = attnW + ((size_t)b * NN + n0 + l31) * MID + l5 * 8;
    #pragma unroll
    for (int ds = 0; ds < 8; ++ds)
        bf[ds] = *(const half8_t*)(brow + ds * 16);

    #pragma unroll
    for (int i = 0; i < 2; ++i) {
        const int ct = wave * 2 + i;
        floatx16 acc;
        #pragma unroll
        for (int j = 0; j < 16; ++j) acc[j] = 0.f;

        const float* wrow = w4 + (size_t)(ct * 32 + l31) * MID + l5 * 8;
        #pragma unroll
        for (int ds = 0; ds < 8; ++ds) {
            half8_t wf = cvt8(wrow + ds * 16);
            acc = __builtin_amdgcn_mfma_f32_32x32x16_f16(wf, bf[ds], acc, 0, 0, 0);
        }
        #pragma unroll
        for (int j = 0; j < 16; ++j) {
            int c = ct * 32 + (j & 3) + 8 * (j >> 2) + 4 * l5;
            size_t off = ((size_t)b * CC + c) * NN + n0 + l31;
            out[off] = acc[j] + b4[c] + x[off];
        }
    }
}

extern "C" void kernel_launch(void* const* d_in, const int* in_sizes, int n_in,
                              void* d_out, int out_size, void* d_ws, size_t ws_size,
                              hipStream_t stream)
{
    const float* x  = (const float*)d_in[0];
    const float* w1 = (const float*)d_in[1];
    const float* b1 = (const float*)d_in[2];
    const float* w2 = (const float*)d_in[3];
    const float* b2 = (const float*)d_in[4];
    const float* w3 = (const float*)d_in[5];
    const float* b3 = (const float*)d_in[6];
    const float* w4 = (const float*)d_in[7];
    const float* b4 = (const float*)d_in[8];
    float* out = (float*)d_out;

    // ws: Qg f16 | Kg f16 | VtG f16 | attnW f16 | MLg f32 (13.25 MB total)
    // Opart f16 [B][KS][N][128] aliases d_out (KS=4: exactly out_size).
    _Float16* Qg    = (_Float16*)d_ws;
    _Float16* Kg    = Qg + (size_t)BB * NN * MID;
    _Float16* VtG   = Kg + (size_t)BB * NN * MID;
    _Float16* attnW = VtG + (size_t)BB * NN * MID;
    float* MLg      = (float*)(attnW + (size_t)BB * NN * MID);
    _Float16* Opart = (_Float16*)d_out;

    proj_kernel<<<dim3(NN / 32, BB), 256, 0, stream>>>(x, w1, b1, w2, b2, w3, b3, Qg, Kg, VtG);
    // 1D grid: 49 q-blocks x 8 (b,sp); id = q*8 + c so c lands on XCD c.
    attn_kernel<<<dim3((NN / QB) * KS * BB), 512, 0, stream>>>(Qg, Kg, VtG, Opart, MLg);
    comb_kernel<<<dim3(NN / 32, BB), 256, 0, stream>>>(Opart, MLg, attnW);
    epi_kernel<<<dim3(NN / 32, BB), 256, 0, stream>>>(attnW, w4, b4, x, out);
}

// Round 15
// 259.224 us; speedup vs baseline: 1.0859x; 1.0805x over previous
//
#include <hip/hip_runtime.h>

// NonLocalBlock: B=2, C=256, N=D*H*W=6272, mid=128.
// R15 = R12 restored verbatim (session best: 258.8 us).
//  - R13/R14 (8-wave k-half split) refuted: 168us even without spill vs
//    R12's 145us attn. Seven structural attn experiments (async stage,
//    single barrier, T15, XCD swizzle, 2x occupancy, k-split x2) pin attn
//    at 143-145us: intra-wave dep-chain floor for this decomposition.
//  - proj: f16 MFMA split-x, 32-n tiles, 392 blocks.
//  - attn: 4-wave QB=128, KS=4, K/V dbuf + reg prefetch, single barrier,
//    in-reg P (pkrtz+permlane32_swap), exp2 domain, defer-max,
//    XCD (b,sp)%8 panel affinity (FETCH at compulsory 9.5MB).
//  - comb: KS-partial merge; epi: f16 MFMA, 392 blocks.
// ws: Qg f16 | Kg f16 | VtG f16 | attnW f16 | MLg f32 = 13.25 MB.

#define BB  2
#define CC  256
#define NN  6272
#define MID 128
#define KS  4
#define QB  128
#define NT  (NN / 64)
#define LOG2E 1.4426950408889634f

typedef _Float16 half2_t __attribute__((ext_vector_type(2)));
typedef _Float16 half4_t __attribute__((ext_vector_type(4)));
typedef _Float16 half8_t __attribute__((ext_vector_type(8)));
typedef float    floatx16 __attribute__((ext_vector_type(16)));
typedef int      i32x2 __attribute__((ext_vector_type(2)));
typedef unsigned u32x4 __attribute__((ext_vector_type(4)));

__device__ __forceinline__ unsigned pkrtz(float a, float b) {
    return __builtin_bit_cast(unsigned, __builtin_amdgcn_cvt_pkrtz(a, b));
}
__device__ __forceinline__ half8_t cvt8(const float* p) {
    float4 f0 = *(const float4*)p;
    float4 f1 = *(const float4*)(p + 4);
    u32x4 u;
    u[0] = pkrtz(f0.x, f0.y); u[1] = pkrtz(f0.z, f0.w);
    u[2] = pkrtz(f1.x, f1.y); u[3] = pkrtz(f1.z, f1.w);
    return __builtin_bit_cast(half8_t, u);
}

// ---------------------------------------------------------------------------
// Projection (f16 MFMA, split-x, 32-n tiles): e_pj[n][m] = w_pj @ x + bias.
// grid (NN/32, BB) = 392 blocks, block 256 (4 waves).
// ---------------------------------------------------------------------------
__global__ __launch_bounds__(256, 2) void proj_kernel(
    const float* __restrict__ x,
    const float* __restrict__ w1, const float* __restrict__ bi1,
    const float* __restrict__ w2, const float* __restrict__ bi2,
    const float* __restrict__ w3, const float* __restrict__ bi3,
    _Float16* __restrict__ Qg, _Float16* __restrict__ Kg, _Float16* __restrict__ VtG)
{
    const int t    = threadIdx.x;
    const int lane = t & 63;
    const int wave = t >> 6;
    const int l31  = lane & 31;
    const int l5   = lane >> 5;
    const int n0   = blockIdx.x * 32;
    const int b    = blockIdx.y;

    __shared__ _Float16 xhi[32 * 260];   // [n][c], stride 260
    __shared__ _Float16 xlo[32 * 260];

    #pragma unroll
    for (int a = t; a < 512; a += 256) {
        int cg = a >> 3, ng = a & 7;
        int c  = cg * 4, n4 = ng * 4;
        const float* xb = x + ((size_t)b * CC + c) * NN + n0 + n4;
        float4 v0 = *(const float4*)(xb);
        float4 v1 = *(const float4*)(xb + NN);
        float4 v2 = *(const float4*)(xb + 2 * (size_t)NN);
        float4 v3 = *(const float4*)(xb + 3 * (size_t)NN);
        const float* pv[4] = {&v0.x, &v1.x, &v2.x, &v3.x};
        #pragma unroll
        for (int nn = 0; nn < 4; ++nn) {
            half4_t h, l;
            #pragma unroll
            for (int ci = 0; ci < 4; ++ci) {
                float f = pv[ci][nn];
                _Float16 hh = (_Float16)f;
                h[ci] = hh;
                l[ci] = (_Float16)(f - (float)hh);
            }
            *(half4_t*)&xhi[(n4 + nn) * 260 + c] = h;
            *(half4_t*)&xlo[(n4 + nn) * 260 + c] = l;
        }
    }
    __syncthreads();

    floatx16 acc[3];
    #pragma unroll
    for (int i = 0; i < 3; ++i)
        #pragma unroll
        for (int j = 0; j < 16; ++j) acc[i][j] = 0.f;

    #pragma unroll
    for (int i = 0; i < 3; ++i) {
        const int tau = wave * 3 + i;
        const int pj = tau >> 2, mt = tau & 3;
        const float* w = (pj == 0) ? w1 : (pj == 1) ? w2 : w3;
        const float* wrow = w + (size_t)(mt * 32 + l31) * CC + l5 * 8;
        const _Float16* xr_hi = xhi + l31 * 260 + l5 * 8;
        const _Float16* xr_lo = xlo + l31 * 260 + l5 * 8;
        #pragma unroll
        for (int ds = 0; ds < 16; ++ds) {
            half8_t wf = cvt8(wrow + ds * 16);
            half8_t ah = *(const half8_t*)(xr_hi + ds * 16);
            half8_t al = *(const half8_t*)(xr_lo + ds * 16);
            if (pj < 2) {
                acc[i] = __builtin_amdgcn_mfma_f32_32x32x16_f16(ah, wf, acc[i], 0, 0, 0);
                acc[i] = __builtin_amdgcn_mfma_f32_32x32x16_f16(al, wf, acc[i], 0, 0, 0);
            } else {
                acc[i] = __builtin_amdgcn_mfma_f32_32x32x16_f16(wf, ah, acc[i], 0, 0, 0);
                acc[i] = __builtin_amdgcn_mfma_f32_32x32x16_f16(wf, al, acc[i], 0, 0, 0);
            }
        }
    }

    #pragma unroll
    for (int i = 0; i < 3; ++i) {
        const int tau = wave * 3 + i;
        const int pj = tau >> 2, mt = tau & 3;
        if (pj < 2) {
            const float bm = ((pj == 0) ? bi1 : bi2)[mt * 32 + l31];
            const float sc = (pj == 0) ? LOG2E : 1.0f;
            _Float16* eo = ((pj == 0) ? Qg : Kg) + (size_t)b * NN * MID;
            #pragma unroll
            for (int j = 0; j < 16; ++j) {
                int n = n0 + (j & 3) + 8 * (j >> 2) + 4 * l5;
                eo[(size_t)n * MID + mt * 32 + l31] = (_Float16)((acc[i][j] + bm) * sc);
            }
        } else {
            _Float16* eo = VtG + (size_t)b * MID * NN;
            #pragma unroll
            for (int j = 0; j < 16; ++j) {
                int m = mt * 32 + (j & 3) + 8 * (j >> 2) + 4 * l5;
                eo[(size_t)m * NN + n0 + l31] = (_Float16)(acc[i][j] + bi3[m]);
            }
        }
    }
}

// ---------------------------------------------------------------------------
// Flash attention partial (R9 loop + XCD panel-affinity swizzle).
// grid: 1D 392; id n: c8 = n%8 -> (b,sp) panel (= XCD), q-block = n/8.
// LDS (69632 B): Ks0 | Ks1 [64][136] | Vt0 | Vt1 [128][68].
// ---------------------------------------------------------------------------
__global__ __launch_bounds__(256, 2) void attn_kernel(
    const _Float16* __restrict__ Qg, const _Float16* __restrict__ Kg,
    const _Float16* __restrict__ VtG, _Float16* __restrict__ Opart,
    float* __restrict__ MLg)
{
    const int t    = threadIdx.x;
    const int lane = t & 63;
    const int wave = t >> 6;        // q-strip owner (0..3)
    const int l31  = lane & 31;
    const int l5   = lane >> 5;
    const int c8   = blockIdx.x & 7;    // (b,sp) combo -> XCD
    const int b    = c8 >> 2;
    const int sp   = c8 & 3;
    const int q0   = (blockIdx.x >> 3) * QB;
    const int kt0  = (NT * sp) / KS;
    const int kt1  = (NT * (sp + 1)) / KS;

    __shared__ __align__(16) char lds[69632];
    _Float16* Ks0 = (_Float16*)lds;               // 64*136 halfs
    _Float16* Ks1 = (_Float16*)(lds + 17408);
    _Float16* Vt0 = (_Float16*)(lds + 34816);     // 128*68 halfs
    _Float16* Vt1 = (_Float16*)(lds + 52224);
    _Float16* Osh = (_Float16*)lds;               // [128][136] alias (Ks0+Ks1)

    const _Float16* Qb = Qg + ((size_t)b * NN + q0 + wave * 32) * MID;
    const _Float16* Kb = Kg + (size_t)b * NN * MID;
    const _Float16* Vb = VtG + (size_t)b * MID * NN;

    half8_t qf[8];
    #pragma unroll
    for (int ds = 0; ds < 8; ++ds)
        qf[ds] = *(const half8_t*)(Qb + (size_t)l31 * MID + ds * 16 + l5 * 8);

    floatx16 o[4];
    #pragma unroll
    for (int dt = 0; dt < 4; ++dt)
        #pragma unroll
        for (int j = 0; j < 16; ++j) o[dt][j] = 0.f;
    float m_run = -3.0e38f, l_run = 0.f;   // m in log2 domain

    const int krow_t = t >> 4, koff_t = (t & 15) * 8;
    const int vd_t   = t >> 3, voff_t = (t & 7) * 8;

    // ---- prologue: stage K[kt0] -> Ks0, V[kt0] -> Vt0 ----
    #pragma unroll
    for (int it = 0; it < 4; ++it) {
        int r = it * 16 + krow_t;
        *(half8_t*)(Ks0 + r * 136 + koff_t) =
            *(const half8_t*)(Kb + (size_t)(kt0 * 64 + r) * MID + koff_t);
    }
    #pragma unroll
    for (int it = 0; it < 4; ++it) {
        int d = it * 32 + vd_t;
        *(half8_t*)(Vt0 + d * 68 + voff_t) =
            *(const half8_t*)(Vb + (size_t)d * NN + kt0 * 64 + voff_t);
    }
    __syncthreads();

    for (int kt = kt0, cbuf = 0; kt < kt1; ++kt, cbuf ^= 1) {
        const int nk = kt * 64;
        _Float16* KBcur = cbuf ? Ks1 : Ks0;
        _Float16* KBnxt = cbuf ? Ks0 : Ks1;
        _Float16* VBcur = cbuf ? Vt1 : Vt0;
        _Float16* VBnxt = cbuf ? Vt0 : Vt1;

        // ---- issue K[kt+1], V[kt+1] global loads -> regs (EARLY) ----
        const int nk2 = (kt + 1 < kt1) ? nk + 64 : nk;   // tail: harmless reload
        half8_t vreg[4], kreg[4];
        #pragma unroll
        for (int it = 0; it < 4; ++it)
            vreg[it] = *(const half8_t*)(Vb + (size_t)(it * 32 + vd_t) * NN + nk2 + voff_t);
        #pragma unroll
        for (int it = 0; it < 4; ++it)
            kreg[it] = *(const half8_t*)(Kb + (size_t)(nk2 + it * 16 + krow_t) * MID + koff_t);
        __builtin_amdgcn_sched_barrier(0);   // pin the loads above this point

        // ---- S^T strips from KBcur (staged last iter) ----
        floatx16 s0, s1;
        #pragma unroll
        for (int j = 0; j < 16; ++j) { s0[j] = 0.f; s1[j] = 0.f; }
        const _Float16* krow0 = KBcur + l31 * 136 + l5 * 8;
        const _Float16* krow1 = KBcur + (32 + l31) * 136 + l5 * 8;
        __builtin_amdgcn_s_setprio(1);
        #pragma unroll
        for (int ds = 0; ds < 8; ++ds) {
            s0 = __builtin_amdgcn_mfma_f32_32x32x16_f16(
                     *(const half8_t*)(krow0 + ds * 16), qf[ds], s0, 0, 0, 0);
            s1 = __builtin_amdgcn_mfma_f32_32x32x16_f16(
                     *(const half8_t*)(krow1 + ds * 16), qf[ds], s1, 0, 0, 0);
        }
        __builtin_amdgcn_s_setprio(0);

        // ---- online softmax over 64 k' ----
        float tmax = fmaxf(s0[0], s1[0]);
        #pragma unroll
        for (int j = 1; j < 16; ++j) tmax = fmaxf(tmax, fmaxf(s0[j], s1[j]));
        tmax = fmaxf(tmax, __shfl_xor(tmax, 32));

        if (!__all(tmax <= m_run)) {     // defer-max THR=0 (exact)
            const float m_new = fmaxf(m_run, tmax);
            const float alpha = exp2f(m_run - m_new);
            m_run = m_new;
            l_run *= alpha;
            #pragma unroll
            for (int dt = 0; dt < 4; ++dt)
                #pragma unroll
                for (int j = 0; j < 16; ++j) o[dt][j] *= alpha;
        }

        float psum = 0.f;
        unsigned u0[8], u1[8];
        #pragma unroll
        for (int g = 0; g < 4; ++g) {
            float p0 = exp2f(s0[4 * g + 0] - m_run);
            float p1 = exp2f(s0[4 * g + 1] - m_run);
            float p2 = exp2f(s0[4 * g + 2] - m_run);
            float p3 = exp2f(s0[4 * g + 3] - m_run);
            psum += (p0 + p1) + (p2 + p3);
            u0[g] = pkrtz(p0, p1);
            u1[g] = pkrtz(p2, p3);
        }
        #pragma unroll
        for (int g = 0; g < 4; ++g) {
            float p0 = exp2f(s1[4 * g + 0] - m_run);
            float p1 = exp2f(s1[4 * g + 1] - m_run);
            float p2 = exp2f(s1[4 * g + 2] - m_run);
            float p3 = exp2f(s1[4 * g + 3] - m_run);
            psum += (p0 + p1) + (p2 + p3);
            u0[4 + g] = pkrtz(p0, p1);
            u1[4 + g] = pkrtz(p2, p3);
        }
        psum += __shfl_xor(psum, 32);
        l_run += psum;

        // ---- write K/V[kt+1] to the other buffers (nobody reads them now) ----
        #pragma unroll
        for (int it = 0; it < 4; ++it)
            *(half8_t*)(VBnxt + (it * 32 + vd_t) * 68 + voff_t) = vreg[it];
        #pragma unroll
        for (int it = 0; it < 4; ++it)
            *(half8_t*)(KBnxt + (it * 16 + krow_t) * 136 + koff_t) = kreg[it];

        // ---- O^T += V^T . P^T from VBcur (staged last iter) ----
        __builtin_amdgcn_s_setprio(1);
        #pragma unroll
        for (int ks = 0; ks < 4; ++ks) {
            i32x2 rA = __builtin_amdgcn_permlane32_swap(
                           (int)u0[2 * ks], (int)u0[2 * ks + 1], false, false);
            i32x2 rB = __builtin_amdgcn_permlane32_swap(
                           (int)u1[2 * ks], (int)u1[2 * ks + 1], false, false);
            u32x4 pw;
            pw[0] = (unsigned)rA[0]; pw[1] = (unsigned)rB[0];
            pw[2] = (unsigned)rA[1]; pw[3] = (unsigned)rB[1];
            half8_t pf = __builtin_bit_cast(half8_t, pw);
            const _Float16* vcol = VBcur + ks * 16 + l5 * 8;
            #pragma unroll
            for (int dt = 0; dt < 4; ++dt)
                o[dt] = __builtin_amdgcn_mfma_f32_32x32x16_f16(
                            *(const half8_t*)(vcol + (dt * 32 + l31) * 68), pf,
                            o[dt], 0, 0, 0);
        }
        __builtin_amdgcn_s_setprio(0);

        __syncthreads();   // ONE barrier: this iter's reads of cur vs next writes
    }

    // ---- per-row (m,l); transpose O via LDS; store UNNORMALIZED f16 ----
    if (l5 == 0) {
        float* mlb = MLg + ((size_t)(b * KS + sp) * 2) * NN;
        mlb[q0 + wave * 32 + l31]      = m_run;
        mlb[NN + q0 + wave * 32 + l31] = l_run;
    }

    #pragma unroll
    for (int dt = 0; dt < 4; ++dt)
        #pragma unroll
        for (int h = 0; h < 4; ++h) {
            half4_t v;
            #pragma unroll
            for (int i = 0; i < 4; ++i) v[i] = (_Float16)o[dt][4 * h + i];
            *(half4_t*)(Osh + (wave * 32 + l31) * 136 + dt * 32 + 8 * h + 4 * l5) = v;
        }
    __syncthreads();
    _Float16* Ob = Opart + ((size_t)(b * KS + sp) * NN + q0) * MID;
    #pragma unroll
    for (int it = 0; it < 8; ++it) {
        int c = it * 256 + t;
        int q = c >> 4, g = c & 15;
        *(half8_t*)(Ob + (size_t)q * MID + g * 8) =
            *(const half8_t*)(Osh + q * 136 + g * 8);
    }
}

// ---------------------------------------------------------------------------
// Combine the KS partials — UNCHANGED.
// ---------------------------------------------------------------------------
__global__ __launch_bounds__(256, 4) void comb_kernel(
    const _Float16* __restrict__ Opart, const float* __restrict__ MLg,
    _Float16* __restrict__ attnW)
{
    const int t  = threadIdx.x;
    const int b  = blockIdx.y;
    const int q  = blockIdx.x * 32 + (t >> 3);
    const int dg = (t & 7) * 16;

    float mv[KS], lv[KS];
    float m_g = -3.0e38f;
    #pragma unroll
    for (int s = 0; s < KS; ++s) {
        const float* mlb = MLg + ((size_t)(b * KS + s) * 2) * NN;
        mv[s] = mlb[q];
        lv[s] = mlb[NN + q];
        m_g = fmaxf(m_g, mv[s]);
    }
    float lg = 0.f, w[KS];
    #pragma unroll
    for (int s = 0; s < KS; ++s) { w[s] = exp2f(mv[s] - m_g); lg += lv[s] * w[s]; }
    const float inv = 1.0f / lg;

    float acc[16];
    #pragma unroll
    for (int j = 0; j < 16; ++j) acc[j] = 0.f;
    #pragma unroll
    for (int s = 0; s < KS; ++s) {
        const half8_t* Op = (const half8_t*)(Opart + ((size_t)(b * KS + s) * NN + q) * MID + dg);
        half8_t v0 = Op[0], v1 = Op[1];
        #pragma unroll
        for (int j = 0; j < 8; ++j) {
            acc[j]     += (float)v0[j] * w[s];
            acc[8 + j] += (float)v1[j] * w[s];
        }
    }
    half8_t h0, h1;
    #pragma unroll
    for (int j = 0; j < 8; ++j) {
        h0[j] = (_Float16)(acc[j] * inv);
        h1[j] = (_Float16)(acc[8 + j] * inv);
    }
    half8_t* Ow = (half8_t*)(attnW + ((size_t)b * NN + q) * MID + dg);
    Ow[0] = h0; Ow[1] = h1;
}

// ---------------------------------------------------------------------------
// Epilogue (f16 MFMA, no LDS, 32-n tiles): out = x + w4 @ attn^T + b4.
// grid (NN/32, BB) = 392 blocks, block 256 (4 waves).
// ---------------------------------------------------------------------------
__global__ __launch_bounds__(256, 2) void epi_kernel(
    const _Float16* __restrict__ attnW, const float* __restrict__ w4,
    const float* __restrict__ b4, const float* __restrict__ x,
    float* __restrict__ out)
{
    const int t    = threadIdx.x;
    const int lane = t & 63;
    const int wave = t >> 6;
    const int l31  = lane & 31;
    const int l5   = lane >> 5;
    const int n0   = blockIdx.x * 32;
    const int b    = blockIdx.y;

    // B-frags: row n = n0 + l31, shared by both c-tiles of this wave.
    half8_t bf[8];
    const _Float16* brow = attnW + ((size_t)b * NN + n0 + l31) * MID + l5 * 8;
    #pragma unroll
    for (int ds = 0; ds < 8; ++ds)
        bf[ds] = *(const half8_t*)(brow + ds * 16);

    #pragma unroll
    for (int i = 0; i < 2; ++i) {
        const int ct = wave * 2 + i;
        floatx16 acc;
        #pragma unroll
        for (int j = 0; j < 16; ++j) acc[j] = 0.f;

        const float* wrow = w4 + (size_t)(ct * 32 + l31) * MID + l5 * 8;
        #pragma unroll
        for (int ds = 0; ds < 8; ++ds) {
            half8_t wf = cvt8(wrow + ds * 16);
            acc = __builtin_amdgcn_mfma_f32_32x32x16_f16(wf, bf[ds], acc, 0, 0, 0);
        }
        // D[c][n]: lane col n = n0+l31; rows c = ct*32 + rowof(j)
        #pragma unroll
        for (int j = 0; j < 16; ++j) {
            int c = ct * 32 + (j & 3) + 8 * (j >> 2) + 4 * l5;
            size_t off = ((size_t)b * CC + c) * NN + n0 + l31;
            out[off] = acc[j] + b4[c] + x[off];
        }
    }
}

extern "C" void kernel_launch(void* const* d_in, const int* in_sizes, int n_in,
                              void* d_out, int out_size, void* d_ws, size_t ws_size,
                              hipStream_t stream)
{
    const float* x  = (const float*)d_in[0];
    const float* w1 = (const float*)d_in[1];
    const float* b1 = (const float*)d_in[2];
    const float* w2 = (const float*)d_in[3];
    const float* b2 = (const float*)d_in[4];
    const float* w3 = (const float*)d_in[5];
    const float* b3 = (const float*)d_in[6];
    const float* w4 = (const float*)d_in[7];
    const float* b4 = (const float*)d_in[8];
    float* out = (float*)d_out;

    // ws: Qg f16 | Kg f16 | VtG f16 | attnW f16 | MLg f32 (13.25 MB total)
    // Opart f16 [B][KS][N][128] aliases d_out (KS=4: exactly out_size).
    _Float16* Qg    = (_Float16*)d_ws;
    _Float16* Kg    = Qg + (size_t)BB * NN * MID;
    _Float16* VtG   = Kg + (size_t)BB * NN * MID;
    _Float16* attnW = VtG + (size_t)BB * NN * MID;
    float* MLg      = (float*)(attnW + (size_t)BB * NN * MID);
    _Float16* Opart = (_Float16*)d_out;

    proj_kernel<<<dim3(NN / 32, BB), 256, 0, stream>>>(x, w1, b1, w2, b2, w3, b3, Qg, Kg, VtG);
    // 1D grid: 49 q-blocks x 8 (b,sp); id = q*8 + c so c lands on XCD c.
    attn_kernel<<<dim3((NN / QB) * KS * BB), 256, 0, stream>>>(Qg, Kg, VtG, Opart, MLg);
    comb_kernel<<<dim3(NN / 32, BB), 256, 0, stream>>>(Opart, MLg, attnW);
    epi_kernel<<<dim3(NN / 32, BB), 256, 0, stream>>>(attnW, w4, b4, x, out);
}

// Round 17
// 254.480 us; speedup vs baseline: 1.1061x; 1.0186x over previous
//
#include <hip/hip_runtime.h>

// NonLocalBlock: B=2, C=256, N=D*H*W=6272, mid=128.
// R17 = R15 + comb->epi fusion done SAFELY (R16 failed on d_out aliasing:
// fused epi wrote out into the same buffer it was still reading Opart from).
//  - Runtime branch on ws_size: if ws >= 22.88MB, Opart lives in WS and the
//    fused epi (in-register KS-merge) runs — zero aliasing (attn writes ws;
//    epi reads ws, writes d_out). Else: R15 path verbatim (Opart in d_out,
//    comb -> attnW -> epi), proven 259us.
//  - proj / attn byte-identical to R15 (session best, reproduced twice).
// ws fused: Qg|Kg|VtG f16 + MLg f32 + Opart f16 = 22.88 MB.
// ws comb:  Qg|Kg|VtG f16 + attnW f16 + MLg f32 = 13.25 MB.

#define BB  2
#define CC  256
#define NN  6272
#define MID 128
#define KS  4
#define QB  128
#define NT  (NN / 64)
#define LOG2E 1.4426950408889634f

typedef _Float16 half2_t __attribute__((ext_vector_type(2)));
typedef _Float16 half4_t __attribute__((ext_vector_type(4)));
typedef _Float16 half8_t __attribute__((ext_vector_type(8)));
typedef float    floatx16 __attribute__((ext_vector_type(16)));
typedef int      i32x2 __attribute__((ext_vector_type(2)));
typedef unsigned u32x4 __attribute__((ext_vector_type(4)));

__device__ __forceinline__ unsigned pkrtz(float a, float b) {
    return __builtin_bit_cast(unsigned, __builtin_amdgcn_cvt_pkrtz(a, b));
}
__device__ __forceinline__ half8_t cvt8(const float* p) {
    float4 f0 = *(const float4*)p;
    float4 f1 = *(const float4*)(p + 4);
    u32x4 u;
    u[0] = pkrtz(f0.x, f0.y); u[1] = pkrtz(f0.z, f0.w);
    u[2] = pkrtz(f1.x, f1.y); u[3] = pkrtz(f1.z, f1.w);
    return __builtin_bit_cast(half8_t, u);
}

// ---------------------------------------------------------------------------
// Projection (f16 MFMA, split-x, 32-n tiles) — UNCHANGED from R15.
// grid (NN/32, BB) = 392 blocks, block 256 (4 waves).
// ---------------------------------------------------------------------------
__global__ __launch_bounds__(256, 2) void proj_kernel(
    const float* __restrict__ x,
    const float* __restrict__ w1, const float* __restrict__ bi1,
    const float* __restrict__ w2, const float* __restrict__ bi2,
    const float* __restrict__ w3, const float* __restrict__ bi3,
    _Float16* __restrict__ Qg, _Float16* __restrict__ Kg, _Float16* __restrict__ VtG)
{
    const int t    = threadIdx.x;
    const int lane = t & 63;
    const int wave = t >> 6;
    const int l31  = lane & 31;
    const int l5   = lane >> 5;
    const int n0   = blockIdx.x * 32;
    const int b    = blockIdx.y;

    __shared__ _Float16 xhi[32 * 260];   // [n][c], stride 260
    __shared__ _Float16 xlo[32 * 260];

    #pragma unroll
    for (int a = t; a < 512; a += 256) {
        int cg = a >> 3, ng = a & 7;
        int c  = cg * 4, n4 = ng * 4;
        const float* xb = x + ((size_t)b * CC + c) * NN + n0 + n4;
        float4 v0 = *(const float4*)(xb);
        float4 v1 = *(const float4*)(xb + NN);
        float4 v2 = *(const float4*)(xb + 2 * (size_t)NN);
        float4 v3 = *(const float4*)(xb + 3 * (size_t)NN);
        const float* pv[4] = {&v0.x, &v1.x, &v2.x, &v3.x};
        #pragma unroll
        for (int nn = 0; nn < 4; ++nn) {
            half4_t h, l;
            #pragma unroll
            for (int ci = 0; ci < 4; ++ci) {
                float f = pv[ci][nn];
                _Float16 hh = (_Float16)f;
                h[ci] = hh;
                l[ci] = (_Float16)(f - (float)hh);
            }
            *(half4_t*)&xhi[(n4 + nn) * 260 + c] = h;
            *(half4_t*)&xlo[(n4 + nn) * 260 + c] = l;
        }
    }
    __syncthreads();

    floatx16 acc[3];
    #pragma unroll
    for (int i = 0; i < 3; ++i)
        #pragma unroll
        for (int j = 0; j < 16; ++j) acc[i][j] = 0.f;

    #pragma unroll
    for (int i = 0; i < 3; ++i) {
        const int tau = wave * 3 + i;
        const int pj = tau >> 2, mt = tau & 3;
        const float* w = (pj == 0) ? w1 : (pj == 1) ? w2 : w3;
        const float* wrow = w + (size_t)(mt * 32 + l31) * CC + l5 * 8;
        const _Float16* xr_hi = xhi + l31 * 260 + l5 * 8;
        const _Float16* xr_lo = xlo + l31 * 260 + l5 * 8;
        #pragma unroll
        for (int ds = 0; ds < 16; ++ds) {
            half8_t wf = cvt8(wrow + ds * 16);
            half8_t ah = *(const half8_t*)(xr_hi + ds * 16);
            half8_t al = *(const half8_t*)(xr_lo + ds * 16);
            if (pj < 2) {
                acc[i] = __builtin_amdgcn_mfma_f32_32x32x16_f16(ah, wf, acc[i], 0, 0, 0);
                acc[i] = __builtin_amdgcn_mfma_f32_32x32x16_f16(al, wf, acc[i], 0, 0, 0);
            } else {
                acc[i] = __builtin_amdgcn_mfma_f32_32x32x16_f16(wf, ah, acc[i], 0, 0, 0);
                acc[i] = __builtin_amdgcn_mfma_f32_32x32x16_f16(wf, al, acc[i], 0, 0, 0);
            }
        }
    }

    #pragma unroll
    for (int i = 0; i < 3; ++i) {
        const int tau = wave * 3 + i;
        const int pj = tau >> 2, mt = tau & 3;
        if (pj < 2) {
            const float bm = ((pj == 0) ? bi1 : bi2)[mt * 32 + l31];
            const float sc = (pj == 0) ? LOG2E : 1.0f;
            _Float16* eo = ((pj == 0) ? Qg : Kg) + (size_t)b * NN * MID;
            #pragma unroll
            for (int j = 0; j < 16; ++j) {
                int n = n0 + (j & 3) + 8 * (j >> 2) + 4 * l5;
                eo[(size_t)n * MID + mt * 32 + l31] = (_Float16)((acc[i][j] + bm) * sc);
            }
        } else {
            _Float16* eo = VtG + (size_t)b * MID * NN;
            #pragma unroll
            for (int j = 0; j < 16; ++j) {
                int m = mt * 32 + (j & 3) + 8 * (j >> 2) + 4 * l5;
                eo[(size_t)m * NN + n0 + l31] = (_Float16)(acc[i][j] + bi3[m]);
            }
        }
    }
}

// ---------------------------------------------------------------------------
// Flash attention partial — UNCHANGED from R15 (R9 loop + XCD panel swizzle).
// grid: 1D 392; id n: c8 = n%8 -> (b,sp) panel (= XCD), q-block = n/8.
// LDS (69632 B): Ks0 | Ks1 [64][136] | Vt0 | Vt1 [128][68].
// ---------------------------------------------------------------------------
__global__ __launch_bounds__(256, 2) void attn_kernel(
    const _Float16* __restrict__ Qg, const _Float16* __restrict__ Kg,
    const _Float16* __restrict__ VtG, _Float16* __restrict__ Opart,
    float* __restrict__ MLg)
{
    const int t    = threadIdx.x;
    const int lane = t & 63;
    const int wave = t >> 6;        // q-strip owner (0..3)
    const int l31  = lane & 31;
    const int l5   = lane >> 5;
    const int c8   = blockIdx.x & 7;    // (b,sp) combo -> XCD
    const int b    = c8 >> 2;
    const int sp   = c8 & 3;
    const int q0   = (blockIdx.x >> 3) * QB;
    const int kt0  = (NT * sp) / KS;
    const int kt1  = (NT * (sp + 1)) / KS;

    __shared__ __align__(16) char lds[69632];
    _Float16* Ks0 = (_Float16*)lds;               // 64*136 halfs
    _Float16* Ks1 = (_Float16*)(lds + 17408);
    _Float16* Vt0 = (_Float16*)(lds + 34816);     // 128*68 halfs
    _Float16* Vt1 = (_Float16*)(lds + 52224);
    _Float16* Osh = (_Float16*)lds;               // [128][136] alias (Ks0+Ks1)

    const _Float16* Qb = Qg + ((size_t)b * NN + q0 + wave * 32) * MID;
    const _Float16* Kb = Kg + (size_t)b * NN * MID;
    const _Float16* Vb = VtG + (size_t)b * MID * NN;

    half8_t qf[8];
    #pragma unroll
    for (int ds = 0; ds < 8; ++ds)
        qf[ds] = *(const half8_t*)(Qb + (size_t)l31 * MID + ds * 16 + l5 * 8);

    floatx16 o[4];
    #pragma unroll
    for (int dt = 0; dt < 4; ++dt)
        #pragma unroll
        for (int j = 0; j < 16; ++j) o[dt][j] = 0.f;
    float m_run = -3.0e38f, l_run = 0.f;   // m in log2 domain

    const int krow_t = t >> 4, koff_t = (t & 15) * 8;
    const int vd_t   = t >> 3, voff_t = (t & 7) * 8;

    // ---- prologue: stage K[kt0] -> Ks0, V[kt0] -> Vt0 ----
    #pragma unroll
    for (int it = 0; it < 4; ++it) {
        int r = it * 16 + krow_t;
        *(half8_t*)(Ks0 + r * 136 + koff_t) =
            *(const half8_t*)(Kb + (size_t)(kt0 * 64 + r) * MID + koff_t);
    }
    #pragma unroll
    for (int it = 0; it < 4; ++it) {
        int d = it * 32 + vd_t;
        *(half8_t*)(Vt0 + d * 68 + voff_t) =
            *(const half8_t*)(Vb + (size_t)d * NN + kt0 * 64 + voff_t);
    }
    __syncthreads();

    for (int kt = kt0, cbuf = 0; kt < kt1; ++kt, cbuf ^= 1) {
        const int nk = kt * 64;
        _Float16* KBcur = cbuf ? Ks1 : Ks0;
        _Float16* KBnxt = cbuf ? Ks0 : Ks1;
        _Float16* VBcur = cbuf ? Vt1 : Vt0;
        _Float16* VBnxt = cbuf ? Vt0 : Vt1;

        // ---- issue K[kt+1], V[kt+1] global loads -> regs (EARLY) ----
        const int nk2 = (kt + 1 < kt1) ? nk + 64 : nk;   // tail: harmless reload
        half8_t vreg[4], kreg[4];
        #pragma unroll
        for (int it = 0; it < 4; ++it)
            vreg[it] = *(const half8_t*)(Vb + (size_t)(it * 32 + vd_t) * NN + nk2 + voff_t);
        #pragma unroll
        for (int it = 0; it < 4; ++it)
            kreg[it] = *(const half8_t*)(Kb + (size_t)(nk2 + it * 16 + krow_t) * MID + koff_t);
        __builtin_amdgcn_sched_barrier(0);   // pin the loads above this point

        // ---- S^T strips from KBcur (staged last iter) ----
        floatx16 s0, s1;
        #pragma unroll
        for (int j = 0; j < 16; ++j) { s0[j] = 0.f; s1[j] = 0.f; }
        const _Float16* krow0 = KBcur + l31 * 136 + l5 * 8;
        const _Float16* krow1 = KBcur + (32 + l31) * 136 + l5 * 8;
        __builtin_amdgcn_s_setprio(1);
        #pragma unroll
        for (int ds = 0; ds < 8; ++ds) {
            s0 = __builtin_amdgcn_mfma_f32_32x32x16_f16(
                     *(const half8_t*)(krow0 + ds * 16), qf[ds], s0, 0, 0, 0);
            s1 = __builtin_amdgcn_mfma_f32_32x32x16_f16(
                     *(const half8_t*)(krow1 + ds * 16), qf[ds], s1, 0, 0, 0);
        }
        __builtin_amdgcn_s_setprio(0);

        // ---- online softmax over 64 k' ----
        float tmax = fmaxf(s0[0], s1[0]);
        #pragma unroll
        for (int j = 1; j < 16; ++j) tmax = fmaxf(tmax, fmaxf(s0[j], s1[j]));
        tmax = fmaxf(tmax, __shfl_xor(tmax, 32));

        if (!__all(tmax <= m_run)) {     // defer-max THR=0 (exact)
            const float m_new = fmaxf(m_run, tmax);
            const float alpha = exp2f(m_run - m_new);
            m_run = m_new;
            l_run *= alpha;
            #pragma unroll
            for (int dt = 0; dt < 4; ++dt)
                #pragma unroll
                for (int j = 0; j < 16; ++j) o[dt][j] *= alpha;
        }

        float psum = 0.f;
        unsigned u0[8], u1[8];
        #pragma unroll
        for (int g = 0; g < 4; ++g) {
            float p0 = exp2f(s0[4 * g + 0] - m_run);
            float p1 = exp2f(s0[4 * g + 1] - m_run);
            float p2 = exp2f(s0[4 * g + 2] - m_run);
            float p3 = exp2f(s0[4 * g + 3] - m_run);
            psum += (p0 + p1) + (p2 + p3);
            u0[g] = pkrtz(p0, p1);
            u1[g] = pkrtz(p2, p3);
        }
        #pragma unroll
        for (int g = 0; g < 4; ++g) {
            float p0 = exp2f(s1[4 * g + 0] - m_run);
            float p1 = exp2f(s1[4 * g + 1] - m_run);
            float p2 = exp2f(s1[4 * g + 2] - m_run);
            float p3 = exp2f(s1[4 * g + 3] - m_run);
            psum += (p0 + p1) + (p2 + p3);
            u0[4 + g] = pkrtz(p0, p1);
            u1[4 + g] = pkrtz(p2, p3);
        }
        psum += __shfl_xor(psum, 32);
        l_run += psum;

        // ---- write K/V[kt+1] to the other buffers (nobody reads them now) ----
        #pragma unroll
        for (int it = 0; it < 4; ++it)
            *(half8_t*)(VBnxt + (it * 32 + vd_t) * 68 + voff_t) = vreg[it];
        #pragma unroll
        for (int it = 0; it < 4; ++it)
            *(half8_t*)(KBnxt + (it * 16 + krow_t) * 136 + koff_t) = kreg[it];

        // ---- O^T += V^T . P^T from VBcur (staged last iter) ----
        __builtin_amdgcn_s_setprio(1);
        #pragma unroll
        for (int ks = 0; ks < 4; ++ks) {
            i32x2 rA = __builtin_amdgcn_permlane32_swap(
                           (int)u0[2 * ks], (int)u0[2 * ks + 1], false, false);
            i32x2 rB = __builtin_amdgcn_permlane32_swap(
                           (int)u1[2 * ks], (int)u1[2 * ks + 1], false, false);
            u32x4 pw;
            pw[0] = (unsigned)rA[0]; pw[1] = (unsigned)rB[0];
            pw[2] = (unsigned)rA[1]; pw[3] = (unsigned)rB[1];
            half8_t pf = __builtin_bit_cast(half8_t, pw);
            const _Float16* vcol = VBcur + ks * 16 + l5 * 8;
            #pragma unroll
            for (int dt = 0; dt < 4; ++dt)
                o[dt] = __builtin_amdgcn_mfma_f32_32x32x16_f16(
                            *(const half8_t*)(vcol + (dt * 32 + l31) * 68), pf,
                            o[dt], 0, 0, 0);
        }
        __builtin_amdgcn_s_setprio(0);

        __syncthreads();   // ONE barrier: this iter's reads of cur vs next writes
    }

    // ---- per-row (m,l); transpose O via LDS; store UNNORMALIZED f16 ----
    if (l5 == 0) {
        float* mlb = MLg + ((size_t)(b * KS + sp) * 2) * NN;
        mlb[q0 + wave * 32 + l31]      = m_run;
        mlb[NN + q0 + wave * 32 + l31] = l_run;
    }

    #pragma unroll
    for (int dt = 0; dt < 4; ++dt)
        #pragma unroll
        for (int h = 0; h < 4; ++h) {
            half4_t v;
            #pragma unroll
            for (int i = 0; i < 4; ++i) v[i] = (_Float16)o[dt][4 * h + i];
            *(half4_t*)(Osh + (wave * 32 + l31) * 136 + dt * 32 + 8 * h + 4 * l5) = v;
        }
    __syncthreads();
    _Float16* Ob = Opart + ((size_t)(b * KS + sp) * NN + q0) * MID;
    #pragma unroll
    for (int it = 0; it < 8; ++it) {
        int c = it * 256 + t;
        int q = c >> 4, g = c & 15;
        *(half8_t*)(Ob + (size_t)q * MID + g * 8) =
            *(const half8_t*)(Osh + q * 136 + g * 8);
    }
}

// ---------------------------------------------------------------------------
// Combine the KS partials (fallback path) — UNCHANGED from R15.
// ---------------------------------------------------------------------------
__global__ __launch_bounds__(256, 4) void comb_kernel(
    const _Float16* __restrict__ Opart, const float* __restrict__ MLg,
    _Float16* __restrict__ attnW)
{
    const int t  = threadIdx.x;
    const int b  = blockIdx.y;
    const int q  = blockIdx.x * 32 + (t >> 3);
    const int dg = (t & 7) * 16;

    float mv[KS], lv[KS];
    float m_g = -3.0e38f;
    #pragma unroll
    for (int s = 0; s < KS; ++s) {
        const float* mlb = MLg + ((size_t)(b * KS + s) * 2) * NN;
        mv[s] = mlb[q];
        lv[s] = mlb[NN + q];
        m_g = fmaxf(m_g, mv[s]);
    }
    float lg = 0.f, w[KS];
    #pragma unroll
    for (int s = 0; s < KS; ++s) { w[s] = exp2f(mv[s] - m_g); lg += lv[s] * w[s]; }
    const float inv = 1.0f / lg;

    float acc[16];
    #pragma unroll
    for (int j = 0; j < 16; ++j) acc[j] = 0.f;
    #pragma unroll
    for (int s = 0; s < KS; ++s) {
        const half8_t* Op = (const half8_t*)(Opart + ((size_t)(b * KS + s) * NN + q) * MID + dg);
        half8_t v0 = Op[0], v1 = Op[1];
        #pragma unroll
        for (int j = 0; j < 8; ++j) {
            acc[j]     += (float)v0[j] * w[s];
            acc[8 + j] += (float)v1[j] * w[s];
        }
    }
    half8_t h0, h1;
    #pragma unroll
    for (int j = 0; j < 8; ++j) {
        h0[j] = (_Float16)(acc[j] * inv);
        h1[j] = (_Float16)(acc[8 + j] * inv);
    }
    half8_t* Ow = (half8_t*)(attnW + ((size_t)b * NN + q) * MID + dg);
    Ow[0] = h0; Ow[1] = h1;
}

// ---------------------------------------------------------------------------
// Epilogue, plain (fallback path; reads merged attnW) — UNCHANGED from R15.
// ---------------------------------------------------------------------------
__global__ __launch_bounds__(256, 2) void epi_kernel(
    const _Float16* __restrict__ attnW, const float* __restrict__ w4,
    const float* __restrict__ b4, const float* __restrict__ x,
    float* __restrict__ out)
{
    const int t    = threadIdx.x;
    const int lane = t & 63;
    const int wave = t >> 6;
    const int l31  = lane & 31;
    const int l5   = lane >> 5;
    const int n0   = blockIdx.x * 32;
    const int b    = blockIdx.y;

    half8_t bf[8];
    const _Float16* brow = attnW + ((size_t)b * NN + n0 + l31) * MID + l5 * 8;
    #pragma unroll
    for (int ds = 0; ds < 8; ++ds)
        bf[ds] = *(const half8_t*)(brow + ds * 16);

    #pragma unroll
    for (int i = 0; i < 2; ++i) {
        const int ct = wave * 2 + i;
        floatx16 acc;
        #pragma unroll
        for (int j = 0; j < 16; ++j) acc[j] = 0.f;

        const float* wrow = w4 + (size_t)(ct * 32 + l31) * MID + l5 * 8;
        #pragma unroll
        for (int ds = 0; ds < 8; ++ds) {
            half8_t wf = cvt8(wrow + ds * 16);
            acc = __builtin_amdgcn_mfma_f32_32x32x16_f16(wf, bf[ds], acc, 0, 0, 0);
        }
        #pragma unroll
        for (int j = 0; j < 16; ++j) {
            int c = ct * 32 + (j & 3) + 8 * (j >> 2) + 4 * l5;
            size_t off = ((size_t)b * CC + c) * NN + n0 + l31;
            out[off] = acc[j] + b4[c] + x[off];
        }
    }
}

// ---------------------------------------------------------------------------
// Epilogue with FUSED KS-merge (used only when Opart fits in ws — no alias):
// out = x + w4 @ (merge(Opart, MLg))^T + b4. grid (NN/32, BB), block 256.
// ---------------------------------------------------------------------------
__global__ __launch_bounds__(256, 2) void epi_fused_kernel(
    const _Float16* __restrict__ Opart, const float* __restrict__ MLg,
    const float* __restrict__ w4, const float* __restrict__ b4,
    const float* __restrict__ x, float* __restrict__ out)
{
    const int t    = threadIdx.x;
    const int lane = t & 63;
    const int wave = t >> 6;
    const int l31  = lane & 31;
    const int l5   = lane >> 5;
    const int n0   = blockIdx.x * 32;
    const int b    = blockIdx.y;
    const int q    = n0 + l31;      // this lane's attention row

    // ---- per-lane decode weights from the KS partials' (m,l) ----
    float mv[KS], lv[KS];
    float m_g = -3.0e38f;
    #pragma unroll
    for (int s = 0; s < KS; ++s) {
        const float* mlb = MLg + ((size_t)(b * KS + s) * 2) * NN;
        mv[s] = mlb[q];
        lv[s] = mlb[NN + q];
        m_g = fmaxf(m_g, mv[s]);
    }
    float lg = 0.f, ws_[KS];
    #pragma unroll
    for (int s = 0; s < KS; ++s) { ws_[s] = exp2f(mv[s] - m_g); lg += lv[s] * ws_[s]; }
    const float inv = 1.0f / lg;
    #pragma unroll
    for (int s = 0; s < KS; ++s) ws_[s] *= inv;

    // ---- merged B-frags: row n = q, 8 x half8 (shared by both c-tiles) ----
    half8_t bf[8];
    #pragma unroll
    for (int ds = 0; ds < 8; ++ds) {
        float a8[8];
        #pragma unroll
        for (int j = 0; j < 8; ++j) a8[j] = 0.f;
        #pragma unroll
        for (int s = 0; s < KS; ++s) {
            half8_t v = *(const half8_t*)(Opart +
                ((size_t)(b * KS + s) * NN + q) * MID + ds * 16 + l5 * 8);
            #pragma unroll
            for (int j = 0; j < 8; ++j) a8[j] += (float)v[j] * ws_[s];
        }
        u32x4 u;
        u[0] = pkrtz(a8[0], a8[1]); u[1] = pkrtz(a8[2], a8[3]);
        u[2] = pkrtz(a8[4], a8[5]); u[3] = pkrtz(a8[6], a8[7]);
        bf[ds] = __builtin_bit_cast(half8_t, u);
    }

    #pragma unroll
    for (int i = 0; i < 2; ++i) {
        const int ct = wave * 2 + i;
        floatx16 acc;
        #pragma unroll
        for (int j = 0; j < 16; ++j) acc[j] = 0.f;

        const float* wrow = w4 + (size_t)(ct * 32 + l31) * MID + l5 * 8;
        #pragma unroll
        for (int ds = 0; ds < 8; ++ds) {
            half8_t wf = cvt8(wrow + ds * 16);
            acc = __builtin_amdgcn_mfma_f32_32x32x16_f16(wf, bf[ds], acc, 0, 0, 0);
        }
        #pragma unroll
        for (int j = 0; j < 16; ++j) {
            int c = ct * 32 + (j & 3) + 8 * (j >> 2) + 4 * l5;
            size_t off = ((size_t)b * CC + c) * NN + n0 + l31;
            out[off] = acc[j] + b4[c] + x[off];
        }
    }
}

extern "C" void kernel_launch(void* const* d_in, const int* in_sizes, int n_in,
                              void* d_out, int out_size, void* d_ws, size_t ws_size,
                              hipStream_t stream)
{
    const float* x  = (const float*)d_in[0];
    const float* w1 = (const float*)d_in[1];
    const float* b1 = (const float*)d_in[2];
    const float* w2 = (const float*)d_in[3];
    const float* b2 = (const float*)d_in[4];
    const float* w3 = (const float*)d_in[5];
    const float* b3 = (const float*)d_in[6];
    const float* w4 = (const float*)d_in[7];
    const float* b4 = (const float*)d_in[8];
    float* out = (float*)d_out;

    const size_t f16buf = (size_t)BB * NN * MID;           // elements
    const size_t mlg_f  = (size_t)BB * KS * 2 * NN;        // f32 elements
    const size_t opart_e = (size_t)BB * KS * NN * MID;     // f16 elements
    const size_t need_fused = 3 * f16buf * 2 + mlg_f * 4 + opart_e * 2;  // bytes

    _Float16* Qg  = (_Float16*)d_ws;
    _Float16* Kg  = Qg + f16buf;
    _Float16* VtG = Kg + f16buf;

    proj_kernel<<<dim3(NN / 32, BB), 256, 0, stream>>>(x, w1, b1, w2, b2, w3, b3, Qg, Kg, VtG);

    if (ws_size >= need_fused) {
        // Fused path: Opart + MLg in ws (no aliasing with d_out).
        float* MLg      = (float*)(VtG + f16buf);
        _Float16* Opart = (_Float16*)(MLg + mlg_f);
        attn_kernel<<<dim3((NN / QB) * KS * BB), 256, 0, stream>>>(Qg, Kg, VtG, Opart, MLg);
        epi_fused_kernel<<<dim3(NN / 32, BB), 256, 0, stream>>>(Opart, MLg, w4, b4, x, out);
    } else {
        // R15 fallback: Opart in d_out, comb merges into ws attnW, then epi.
        _Float16* attnW = VtG + f16buf;
        float* MLg      = (float*)(attnW + f16buf);
        _Float16* Opart = (_Float16*)d_out;
        attn_kernel<<<dim3((NN / QB) * KS * BB), 256, 0, stream>>>(Qg, Kg, VtG, Opart, MLg);
        comb_kernel<<<dim3(NN / 32, BB), 256, 0, stream>>>(Opart, MLg, attnW);
        epi_kernel<<<dim3(NN / 32, BB), 256, 0, stream>>>(attnW, w4, b4, x, out);
    }
}